// Round 13
// baseline (248.226 us; speedup 1.0000x reference)
//
#include <hip/hip_runtime.h>
#include <hip/hip_bf16.h>

typedef __attribute__((ext_vector_type(8))) short short8;
typedef __attribute__((ext_vector_type(4))) float floatx4;

#define BATCH 8
#define SEQ 2048
#define DMODEL 768
#define NQKV 2304
#define SCALE 0.03608439182435161f

__device__ __forceinline__ ushort f2bf(float f) {
    union { float f; uint u; } in; in.f = f;
    uint u = in.u;
    return (ushort)((u + 0x7FFFu + ((u >> 16) & 1u)) >> 16);
}
__device__ __forceinline__ float bf2f(ushort h) {
    union { uint u; float f; } o; o.u = ((uint)h) << 16;
    return o.f;
}

// async global->LDS, 16B per lane. lds ptr wave-uniform; HW scatters lane*16.
__device__ __forceinline__ void async_copy16(void* lds_uniform, const void* gaddr) {
    __builtin_amdgcn_global_load_lds(
        (const __attribute__((address_space(1))) void*)gaddr,
        (__attribute__((address_space(3))) void*)lds_uniform,
        16, 0, 0);
}

#define BARRIER() asm volatile("s_barrier" ::: "memory")
#define LGKM0()   do { asm volatile("s_waitcnt lgkmcnt(0)" ::: "memory"); \
                       __builtin_amdgcn_sched_barrier(0); } while (0)
#define LGKM_HINT() asm volatile("s_waitcnt lgkmcnt(8)" ::: "memory")
#define VMCNT(n)  asm volatile("s_waitcnt vmcnt(" #n ")" ::: "memory")

// ---------------------------------------------------------------------------
// 256x256 8-phase GEMM template (R6-verified). BK=64, 2 K-tiles/iter, 8 waves
// (2M x 4N), 128KB dynamic LDS, global_load_lds staging with source-side
// chunk-XOR swizzle (slot = c ^ (row&7); ~0 conflicts).
// MODE 0: qkv main, n in [0,2048) only (bias; Q/K row-major; V d<512 -> Vt).
// MODE 1: score (bf16 out).
// ---------------------------------------------------------------------------
template<int MODE, int KT>
__global__ __launch_bounds__(512, 2) void gemm8(
    const ushort* __restrict__ A, const ushort* __restrict__ B,
    const float* __restrict__ bias,
    void* __restrict__ out0, void* __restrict__ out1, void* __restrict__ out2,
    int lda, int ldb)
{
    extern __shared__ __align__(16) ushort lds[];
    const int tid  = threadIdx.x;
    const int w    = tid >> 6, lane = tid & 63;
    const int wr   = w >> 2,  wc   = w & 3;
    const int lr   = lane & 15, kg = lane >> 4;
    const int srow = lane >> 3;
    const int scc  = (lane & 7) ^ srow;

    const int m0 = blockIdx.x * 256, n0 = blockIdx.y * 256;
    const ushort* Abase;
    const ushort* Bbase;
    if (MODE == 0) {
        Abase = A + (size_t)m0 * lda;
        Bbase = B + (size_t)n0 * ldb;
    } else {
        const int b = blockIdx.z;
        Abase = A + ((size_t)(b * SEQ + m0)) * lda;
        Bbase = B + ((size_t)(b * SEQ + n0)) * ldb;
    }

    const ushort* At[2] = { lds,         lds + 32768 };
    const ushort* Bt[2] = { lds + 16384, lds + 49152 };

    #define STG(tile, mat, half) do { if ((tile) < KT) {                          \
        ushort* sb_ = lds + (((tile) & 1) ? 32768 : 0) + ((mat) ? 16384 : 0);     \
        const ushort* g_ = (mat) ? Bbase : Abase;                                 \
        const size_t ld_ = (mat) ? (size_t)ldb : (size_t)lda;                     \
        const int k0_ = (tile) << 6;                                              \
        _Pragma("unroll")                                                         \
        for (int t_ = 0; t_ < 2; ++t_) {                                          \
            const int c8_ = (mat) ? ((w & 3) + ((w >> 2) << 3) + (t_ << 4) + ((half) << 2)) \
                                  : (w + (t_ << 4) + ((half) << 3));              \
            const int row_ = (c8_ << 3) + srow;                                   \
            async_copy16(sb_ + c8_ * 512, g_ + (size_t)row_ * ld_ + k0_ + scc * 8); \
        } } } while (0)

    short8 af[4][2], bf[4][2];
    floatx4 acc[8][4] = {};

    #define LDFRAG(tp, row, c) \
        (*reinterpret_cast<const short8*>(&(tp)[((row) << 6) + ((((c) ^ ((row) & 7))) << 3)]))

    #define READ_A(bufi, mh) do {                                                 \
        _Pragma("unroll") for (int mf_ = 0; mf_ < 4; ++mf_)                       \
        _Pragma("unroll") for (int kk_ = 0; kk_ < 2; ++kk_)                       \
            af[mf_][kk_] = LDFRAG(At[bufi], wr * 128 + ((mh) * 4 + mf_) * 16 + lr, kk_ * 4 + kg); \
    } while (0)
    #define READ_B(bufi, nh) do {                                                 \
        _Pragma("unroll") for (int nf_ = 0; nf_ < 2; ++nf_)                       \
        _Pragma("unroll") for (int kk_ = 0; kk_ < 2; ++kk_)                       \
            bf[(nh) * 2 + nf_][kk_] = LDFRAG(Bt[bufi], wc * 64 + ((nh) * 2 + nf_) * 16 + lr, kk_ * 4 + kg); \
    } while (0)
    #define MFMA_Q(mh, nh) do {                                                   \
        __builtin_amdgcn_s_setprio(1);                                            \
        _Pragma("unroll") for (int mf_ = 0; mf_ < 4; ++mf_)                       \
        _Pragma("unroll") for (int nf_ = 0; nf_ < 2; ++nf_)                       \
        _Pragma("unroll") for (int kk_ = 0; kk_ < 2; ++kk_)                       \
            acc[(mh) * 4 + mf_][(nh) * 2 + nf_] = __builtin_amdgcn_mfma_f32_16x16x32_bf16( \
                af[mf_][kk_], bf[(nh) * 2 + nf_][kk_], acc[(mh) * 4 + mf_][(nh) * 2 + nf_], 0, 0, 0); \
        __builtin_amdgcn_s_setprio(0);                                            \
    } while (0)

    STG(0, 0, 0); STG(0, 1, 0); STG(0, 1, 1); STG(0, 0, 1);
    STG(1, 0, 0); STG(1, 1, 0); STG(1, 1, 1);
    VMCNT(6);
    BARRIER();

    #pragma unroll 1
    for (int it = 0; it < KT / 2; ++it) {
        const int t = 2 * it;
        const bool lastit = (it == KT / 2 - 1);
        // P1
        READ_A(0, 0); READ_B(0, 0);
        STG(t + 1, 0, 1);
        LGKM_HINT();
        BARRIER(); LGKM0();
        MFMA_Q(0, 0);
        BARRIER();
        // P2
        READ_B(0, 1);
        STG(t + 2, 0, 0);
        BARRIER(); LGKM0();
        MFMA_Q(0, 1);
        BARRIER();
        // P3
        READ_A(0, 1);
        STG(t + 2, 1, 0);
        BARRIER(); LGKM0();
        MFMA_Q(1, 0);
        BARRIER();
        // P4
        STG(t + 2, 1, 1);
        BARRIER();
        MFMA_Q(1, 1);
        if (lastit) { VMCNT(0); } else { VMCNT(6); }
        BARRIER();
        // P5
        READ_A(1, 0); READ_B(1, 0);
        STG(t + 2, 0, 1);
        LGKM_HINT();
        BARRIER(); LGKM0();
        MFMA_Q(0, 0);
        BARRIER();
        // P6
        READ_B(1, 1);
        STG(t + 3, 0, 0);
        BARRIER(); LGKM0();
        MFMA_Q(0, 1);
        BARRIER();
        // P7
        READ_A(1, 1);
        STG(t + 3, 1, 0);
        BARRIER(); LGKM0();
        MFMA_Q(1, 0);
        BARRIER();
        // P8
        STG(t + 3, 1, 1);
        BARRIER();
        MFMA_Q(1, 1);
        VMCNT(6);
        BARRIER();
    }

    // ---- Epilogue ----
    const int mrow = m0 + wr * 128;
    const int ncol = n0 + wc * 64;

    if (MODE == 0 && blockIdx.y >= 6) {
        ushort* Vt = (ushort*)out2;
        const int bIdx = m0 >> 11;
        const int ns0  = m0 & 2047;
        #pragma unroll
        for (int nf = 0; nf < 4; ++nf) {
            const int e = ncol + nf * 16 + lr;        // 1536..2047
            const int d = e - 2 * DMODEL;
            const float bv = bias[e];
            ushort* vrow = Vt + ((size_t)bIdx * DMODEL + d) * SEQ + ns0;
            #pragma unroll
            for (int a = 0; a < 8; ++a) {
                const floatx4 v = acc[a][nf];
                uint2 u;
                u.x = (uint)f2bf(v[0] + bv) | ((uint)f2bf(v[1] + bv) << 16);
                u.y = (uint)f2bf(v[2] + bv) | ((uint)f2bf(v[3] + bv) << 16);
                *reinterpret_cast<uint2*>(vrow + wr * 128 + a * 16 + kg * 4) = u;
            }
        }
    } else {
        float* scr = reinterpret_cast<float*>(reinterpret_cast<char*>(lds) + (size_t)w * 9216);
        #pragma unroll
        for (int mh = 0; mh < 2; ++mh) {
            #pragma unroll
            for (int np = 0; np < 2; ++np) {
                #pragma unroll
                for (int mf = 0; mf < 4; ++mf)
                    #pragma unroll
                    for (int nf2 = 0; nf2 < 2; ++nf2) {
                        const floatx4 v = acc[mh * 4 + mf][np * 2 + nf2];
                        #pragma unroll
                        for (int r = 0; r < 4; ++r)
                            scr[(mf * 16 + kg * 4 + r) * 36 + nf2 * 16 + lr] = v[r];
                    }
                asm volatile("s_waitcnt lgkmcnt(0)" ::: "memory");
                __builtin_amdgcn_sched_barrier(0);

                const int c8 = (lane & 3) * 8;
                const int e0 = ncol + np * 32 + c8;
                ushort* dst; int ec; float mul;
                float bs[8] = {0, 0, 0, 0, 0, 0, 0, 0};
                if (MODE == 0) {
                    const bool isQ = e0 < DMODEL;
                    dst = isQ ? (ushort*)out0 : (ushort*)out1;
                    ec  = isQ ? e0 : e0 - DMODEL;
                    mul = isQ ? SCALE : 1.0f;
                    const float4 b0 = *reinterpret_cast<const float4*>(&bias[e0]);
                    const float4 b1 = *reinterpret_cast<const float4*>(&bias[e0 + 4]);
                    bs[0] = b0.x * mul; bs[1] = b0.y * mul;
                    bs[2] = b0.z * mul; bs[3] = b0.w * mul;
                    bs[4] = b1.x * mul; bs[5] = b1.y * mul;
                    bs[6] = b1.z * mul; bs[7] = b1.w * mul;
                } else {
                    dst = (ushort*)out0 + (size_t)blockIdx.z * SEQ * SEQ;
                    ec = e0; mul = 1.0f;
                }
                const size_t ostride = (MODE == 0) ? (size_t)DMODEL : (size_t)SEQ;
                #pragma unroll
                for (int p = 0; p < 4; ++p) {
                    const int row = p * 16 + (lane >> 2);
                    const float4 lo = *reinterpret_cast<const float4*>(&scr[row * 36 + c8]);
                    const float4 hi = *reinterpret_cast<const float4*>(&scr[row * 36 + c8 + 4]);
                    short8 o;
                    o[0] = (short)f2bf(lo.x * mul + bs[0]);
                    o[1] = (short)f2bf(lo.y * mul + bs[1]);
                    o[2] = (short)f2bf(lo.z * mul + bs[2]);
                    o[3] = (short)f2bf(lo.w * mul + bs[3]);
                    o[4] = (short)f2bf(hi.x * mul + bs[4]);
                    o[5] = (short)f2bf(hi.y * mul + bs[5]);
                    o[6] = (short)f2bf(hi.z * mul + bs[6]);
                    o[7] = (short)f2bf(hi.w * mul + bs[7]);
                    *reinterpret_cast<short8*>(
                        &dst[(size_t)(mrow + mh * 64 + row) * ostride + ec]) = o;
                }
                asm volatile("s_waitcnt lgkmcnt(0)" ::: "memory");
                __builtin_amdgcn_sched_barrier(0);
            }
        }
    }
    #undef STG
    #undef LDFRAG
    #undef READ_A
    #undef READ_B
    #undef MFMA_Q
}

// ---------------------------------------------------------------------------
// pv128 (R10-verified): Out[b] = P[b] @ Vt[b]^T. Tile 128x192, BK=64, KT=32,
// 8 waves (per wave 64x48). LDS 80KB -> 2 blocks/CU; grid 16x4x8 = 512 blocks
// = full CU coverage + 2-deep overlap. Counted vmcnt: 5 loads/tile, N=4.
// ---------------------------------------------------------------------------
__global__ __launch_bounds__(512, 4) void pv128(
    const ushort* __restrict__ P, const ushort* __restrict__ V,
    float* __restrict__ Out)
{
    extern __shared__ __align__(16) ushort lds[];
    const int tid  = threadIdx.x;
    const int w    = tid >> 6, lane = tid & 63;
    const int wr   = w >> 2,  wc   = w & 3;
    const int lr   = lane & 15, kg = lane >> 4;
    const int srow = lane >> 3;
    const int scc  = (lane & 7) ^ srow;

    const int m0 = blockIdx.x * 128, n0 = blockIdx.y * 192;
    const int b  = blockIdx.z;
    const ushort* Abase = P + (size_t)b * SEQ * SEQ + (size_t)m0 * SEQ;
    const ushort* Bbase = V + (size_t)b * DMODEL * SEQ + (size_t)n0 * SEQ;

    const ushort* At[2] = { lds,         lds + 8192 };
    const ushort* Bt[2] = { lds + 16384, lds + 28672 };
    const int KT = 32;

    #define STG_A(tile, half) do { if ((tile) < KT) {                             \
        ushort* sb_ = lds + (((tile) & 1) ? 8192 : 0);                            \
        const int k0_ = (tile) << 6;                                              \
        const int c8_ = (w & 3) + ((w >> 2) << 3) + ((half) << 2);                \
        const int row_ = (c8_ << 3) + srow;                                       \
        async_copy16(sb_ + c8_ * 512, Abase + (size_t)row_ * SEQ + k0_ + scc * 8); \
    } } while (0)
    #define STG_B0(tile) do { if ((tile) < KT) {                                  \
        ushort* sb_ = lds + 16384 + (((tile) & 1) ? 12288 : 0);                   \
        const int k0_ = (tile) << 6;                                              \
        _Pragma("unroll")                                                         \
        for (int t_ = 0; t_ < 2; ++t_) {                                          \
            const int idx_ = w * 2 + t_;                                          \
            const int c8_ = (idx_ >> 2) * 6 + (idx_ & 3);                         \
            const int row_ = (c8_ << 3) + srow;                                   \
            async_copy16(sb_ + c8_ * 512, Bbase + (size_t)row_ * SEQ + k0_ + scc * 8); \
        } } } while (0)
    #define STG_B1(tile) do { if ((tile) < KT) {                                  \
        ushort* sb_ = lds + 16384 + (((tile) & 1) ? 12288 : 0);                   \
        const int k0_ = (tile) << 6;                                              \
        const int c8_ = (w >> 1) * 6 + 4 + (w & 1);                               \
        const int row_ = (c8_ << 3) + srow;                                       \
        async_copy16(sb_ + c8_ * 512, Bbase + (size_t)row_ * SEQ + k0_ + scc * 8); \
    } } while (0)

    short8 af[2][2], bf[3][2];
    floatx4 acc[4][3] = {};

    #define LDFRAG(tp, row, c) \
        (*reinterpret_cast<const short8*>(&(tp)[((row) << 6) + ((((c) ^ ((row) & 7))) << 3)]))

    #define READ_A(bufi, mh) do {                                                 \
        _Pragma("unroll") for (int mf_ = 0; mf_ < 2; ++mf_)                       \
        _Pragma("unroll") for (int kk_ = 0; kk_ < 2; ++kk_)                       \
            af[mf_][kk_] = LDFRAG(At[bufi], wr * 64 + ((mh) * 2 + mf_) * 16 + lr, kk_ * 4 + kg); \
    } while (0)
    #define READ_B_N0(bufi) do {                                                  \
        _Pragma("unroll") for (int nf_ = 0; nf_ < 2; ++nf_)                       \
        _Pragma("unroll") for (int kk_ = 0; kk_ < 2; ++kk_)                       \
            bf[nf_][kk_] = LDFRAG(Bt[bufi], wc * 48 + nf_ * 16 + lr, kk_ * 4 + kg); \
    } while (0)
    #define READ_B_N1(bufi) do {                                                  \
        _Pragma("unroll") for (int kk_ = 0; kk_ < 2; ++kk_)                       \
            bf[2][kk_] = LDFRAG(Bt[bufi], wc * 48 + 32 + lr, kk_ * 4 + kg);       \
    } while (0)
    #define MFMA_N0(mh) do {                                                      \
        __builtin_amdgcn_s_setprio(1);                                            \
        _Pragma("unroll") for (int mf_ = 0; mf_ < 2; ++mf_)                       \
        _Pragma("unroll") for (int nf_ = 0; nf_ < 2; ++nf_)                       \
        _Pragma("unroll") for (int kk_ = 0; kk_ < 2; ++kk_)                       \
            acc[(mh) * 2 + mf_][nf_] = __builtin_amdgcn_mfma_f32_16x16x32_bf16(   \
                af[mf_][kk_], bf[nf_][kk_], acc[(mh) * 2 + mf_][nf_], 0, 0, 0);   \
        __builtin_amdgcn_s_setprio(0);                                            \
    } while (0)
    #define MFMA_N1(mh) do {                                                      \
        __builtin_amdgcn_s_setprio(1);                                            \
        _Pragma("unroll") for (int mf_ = 0; mf_ < 2; ++mf_)                       \
        _Pragma("unroll") for (int kk_ = 0; kk_ < 2; ++kk_)                       \
            acc[(mh) * 2 + mf_][2] = __builtin_amdgcn_mfma_f32_16x16x32_bf16(     \
                af[mf_][kk_], bf[2][kk_], acc[(mh) * 2 + mf_][2], 0, 0, 0);       \
        __builtin_amdgcn_s_setprio(0);                                            \
    } while (0)

    STG_A(0, 0); STG_B0(0); STG_B1(0); STG_A(0, 1);
    STG_A(1, 0); STG_B0(1); STG_B1(1);
    VMCNT(4);
    BARRIER();

    #pragma unroll 1
    for (int it = 0; it < KT / 2; ++it) {
        const int t = 2 * it;
        const bool lastit = (it == KT / 2 - 1);
        // ---- tile t (buf 0) ----
        // P1
        READ_A(0, 0); READ_B_N0(0);
        STG_A(t + 1, 1);
        BARRIER(); LGKM0();
        MFMA_N0(0);
        BARRIER();
        // P2
        READ_B_N1(0);
        STG_A(t + 2, 0);
        BARRIER(); LGKM0();
        MFMA_N1(0);
        BARRIER();
        // P3
        READ_A(0, 1);
        STG_B0(t + 2);
        BARRIER(); LGKM0();
        MFMA_N0(1);
        BARRIER();
        // P4
        STG_B1(t + 2);
        BARRIER();
        MFMA_N1(1);
        if (lastit) { VMCNT(0); } else { VMCNT(4); }
        BARRIER();
        // ---- tile t+1 (buf 1) ----
        // P5
        READ_A(1, 0); READ_B_N0(1);
        STG_A(t + 2, 1);
        BARRIER(); LGKM0();
        MFMA_N0(0);
        BARRIER();
        // P6
        READ_B_N1(1);
        STG_A(t + 3, 0);
        BARRIER(); LGKM0();
        MFMA_N1(0);
        BARRIER();
        // P7
        READ_A(1, 1);
        STG_B0(t + 3);
        BARRIER(); LGKM0();
        MFMA_N0(1);
        BARRIER();
        // P8
        STG_B1(t + 3);
        BARRIER();
        MFMA_N1(1);
        VMCNT(4);
        BARRIER();
    }

    // Epilogue: per-wave scratch [64 rows][stride 20] fp32 = 5120 B.
    const int mrow = m0 + wr * 64;
    const int ncol = n0 + wc * 48;
    float* scr = reinterpret_cast<float*>(reinterpret_cast<char*>(lds) + (size_t)w * 5120);
    float* Ob = Out + (size_t)b * SEQ * DMODEL;
    #pragma unroll
    for (int np = 0; np < 3; ++np) {
        #pragma unroll
        for (int mf = 0; mf < 4; ++mf) {
            const floatx4 v = acc[mf][np];
            #pragma unroll
            for (int r = 0; r < 4; ++r)
                scr[(mf * 16 + kg * 4 + r) * 20 + lr] = v[r];
        }
        asm volatile("s_waitcnt lgkmcnt(0)" ::: "memory");
        __builtin_amdgcn_sched_barrier(0);

        const int c4 = (lane & 3) * 4;
        #pragma unroll
        for (int p = 0; p < 4; ++p) {
            const int row = p * 16 + (lane >> 2);
            const float4 v = *reinterpret_cast<const float4*>(&scr[row * 20 + c4]);
            *reinterpret_cast<float4*>(
                &Ob[(size_t)(mrow + row) * DMODEL + ncol + np * 16 + c4]) = v;
        }
        asm volatile("s_waitcnt lgkmcnt(0)" ::: "memory");
        __builtin_amdgcn_sched_barrier(0);
    }
    #undef STG_A
    #undef STG_B0
    #undef STG_B1
    #undef LDFRAG
    #undef READ_A
    #undef READ_B_N0
    #undef READ_B_N1
    #undef MFMA_N0
    #undef MFMA_N1
}

// ---------------------------------------------------------------------------
// qkv V-tail: cols 2048..2303 (V d in [512,768)). 128x128 tile, BK=32,
// 4 waves, 16KB LDS; V stored transposed to Vt (R8-validated).
// ---------------------------------------------------------------------------
__global__ __launch_bounds__(256) void qkv_vtail(
    const ushort* __restrict__ Xb,
    const ushort* __restrict__ Wt,
    const float* __restrict__ bias,
    ushort* __restrict__ Vt)
{
    __shared__ __align__(16) ushort smem[2 * 128 * 32];
    ushort* As = smem;
    ushort* Bs = smem + 128 * 32;
    const int tid  = threadIdx.x;
    const int m0   = blockIdx.x * 128;
    const int n0   = 2048 + blockIdx.y * 128;
    const int wave = tid >> 6, lane = tid & 63;
    const int wm   = (wave >> 1) * 64, wn = (wave & 1) * 64;
    const int lr   = lane & 15, kg = lane >> 4;
    const ushort* Abase = Xb + (size_t)m0 * DMODEL;
    const ushort* Bbase = Wt + (size_t)n0 * DMODEL;
    floatx4 acc[4][4] = {};

    for (int k0 = 0; k0 < DMODEL; k0 += 32) {
        #pragma unroll
        for (int t = 0; t < 2; ++t) {
            const int chunk = wave * 2 + t;
            const int row = chunk * 16 + (lane >> 2);
            async_copy16(As + chunk * 512,
                         Abase + (size_t)row * DMODEL + k0 + (lane & 3) * 8);
        }
        #pragma unroll
        for (int t = 0; t < 2; ++t) {
            const int chunk = wave * 2 + t;
            const int row = chunk * 16 + (lane >> 2);
            async_copy16(Bs + chunk * 512,
                         Bbase + (size_t)row * DMODEL + k0 + (lane & 3) * 8);
        }
        __syncthreads();
        short8 a[4], b[4];
        #pragma unroll
        for (int i = 0; i < 4; ++i)
            a[i] = *reinterpret_cast<const short8*>(&As[(wm + i * 16 + lr) * 32 + kg * 8]);
        #pragma unroll
        for (int j = 0; j < 4; ++j)
            b[j] = *reinterpret_cast<const short8*>(&Bs[(wn + j * 16 + lr) * 32 + kg * 8]);
        #pragma unroll
        for (int i = 0; i < 4; ++i)
            #pragma unroll
            for (int j = 0; j < 4; ++j)
                acc[i][j] = __builtin_amdgcn_mfma_f32_16x16x32_bf16(a[i], b[j], acc[i][j], 0, 0, 0);
        __syncthreads();
    }

    const int bIdx = m0 >> 11;
    const int ns0  = m0 & 2047;
    #pragma unroll
    for (int j = 0; j < 4; ++j) {
        const int e = n0 + wn + j * 16 + lr;      // 2048..2303
        const int d = e - 2 * DMODEL;             // 512..767
        const float bv = bias[e];
        ushort* vrow = Vt + ((size_t)bIdx * DMODEL + d) * SEQ + ns0;
        #pragma unroll
        for (int i = 0; i < 4; ++i) {
            const floatx4 v = acc[i][j];
            uint2 u;
            u.x = (uint)f2bf(v[0] + bv) | ((uint)f2bf(v[1] + bv) << 16);
            u.y = (uint)f2bf(v[2] + bv) | ((uint)f2bf(v[3] + bv) << 16);
            *reinterpret_cast<uint2*>(vrow + wm + i * 16 + kg * 4) = u;
        }
    }
}

// ---------------------------------------------------------------------------
// Kernel 0a: X fp32 -> bf16
// ---------------------------------------------------------------------------
__global__ __launch_bounds__(256) void convert_x(const float* __restrict__ X,
                                                 ushort* __restrict__ Xb) {
    const int total = (BATCH * SEQ * DMODEL) / 8;
    for (int i = blockIdx.x * 256 + threadIdx.x; i < total; i += gridDim.x * 256) {
        const float4 v0 = reinterpret_cast<const float4*>(X)[(size_t)i * 2];
        const float4 v1 = reinterpret_cast<const float4*>(X)[(size_t)i * 2 + 1];
        uint4 u;
        u.x = (uint)f2bf(v0.x) | ((uint)f2bf(v0.y) << 16);
        u.y = (uint)f2bf(v0.z) | ((uint)f2bf(v0.w) << 16);
        u.z = (uint)f2bf(v1.x) | ((uint)f2bf(v1.y) << 16);
        u.w = (uint)f2bf(v1.z) | ((uint)f2bf(v1.w) << 16);
        reinterpret_cast<uint4*>(Xb)[i] = u;
    }
}

// ---------------------------------------------------------------------------
// Kernel 0b: W [768][2304] fp32 -> Wt [2304][768] bf16 (transpose)
// ---------------------------------------------------------------------------
__global__ __launch_bounds__(256) void convert_wt(const float* __restrict__ W,
                                                  ushort* __restrict__ Wt) {
    __shared__ float tile[32][33];
    const int n0 = blockIdx.x * 32, k0 = blockIdx.y * 32;
    const int tx = threadIdx.x & 31, ty = threadIdx.x >> 5;
    #pragma unroll
    for (int i = 0; i < 32; i += 8)
        tile[ty + i][tx] = W[(size_t)(k0 + ty + i) * NQKV + n0 + tx];
    __syncthreads();
    #pragma unroll
    for (int i = 0; i < 32; i += 8)
        Wt[(size_t)(n0 + ty + i) * DMODEL + k0 + tx] = f2bf(tile[tx][ty + i]);
}

// ---------------------------------------------------------------------------
// Kernel 3: row softmax over 2048, in place, bf16. One block per row.
// ---------------------------------------------------------------------------
__global__ __launch_bounds__(256) void softmax_rows(ushort* __restrict__ S) {
    const int row = blockIdx.x;
    ushort* p = S + (size_t)row * SEQ;
    const int tid = threadIdx.x;
    const int wave = tid >> 6, lane = tid & 63;

    short8 v8 = *reinterpret_cast<const short8*>(p + tid * 8);
    float v[8];
    #pragma unroll
    for (int j = 0; j < 8; ++j) v[j] = bf2f((ushort)v8[j]);
    float mx = v[0];
    #pragma unroll
    for (int j = 1; j < 8; ++j) mx = fmaxf(mx, v[j]);
    #pragma unroll
    for (int off = 32; off >= 1; off >>= 1) mx = fmaxf(mx, __shfl_xor(mx, off));
    __shared__ float redm[4], reds[4];
    if (lane == 0) redm[wave] = mx;
    __syncthreads();
    mx = fmaxf(fmaxf(redm[0], redm[1]), fmaxf(redm[2], redm[3]));

    float e[8], s = 0.f;
    #pragma unroll
    for (int j = 0; j < 8; ++j) { e[j] = __expf(v[j] - mx); s += e[j]; }
    #pragma unroll
    for (int off = 32; off >= 1; off >>= 1) s += __shfl_xor(s, off);
    if (lane == 0) reds[wave] = s;
    __syncthreads();
    s = reds[0] + reds[1] + reds[2] + reds[3];
    float inv = 1.f / s;

    short8 o;
    #pragma unroll
    for (int j = 0; j < 8; ++j) o[j] = (short)f2bf(e[j] * inv);
    *reinterpret_cast<short8*>(p + tid * 8) = o;
}

// ---------------------------------------------------------------------------
extern "C" void kernel_launch(void* const* d_in, const int* in_sizes, int n_in,
                              void* d_out, int out_size, void* d_ws, size_t ws_size,
                              hipStream_t stream) {
    const float* X    = (const float*)d_in[0];
    const float* W    = (const float*)d_in[1];
    const float* bias = (const float*)d_in[2];
    float* Out = (float*)d_out;

    char* ws = (char*)d_ws;
    ushort* S  = (ushort*)ws;
    ushort* Xb = (ushort*)ws;
    ushort* Wt = (ushort*)(ws + (size_t)BATCH * SEQ * DMODEL * 2);
    ushort* Qs = (ushort*)(ws + (size_t)BATCH * SEQ * SEQ * 2);
    ushort* Kb = Qs + (size_t)BATCH * SEQ * DMODEL;
    ushort* Vt = Kb + (size_t)BATCH * SEQ * DMODEL;

    const int LDSB = 131072;
    (void)hipFuncSetAttribute((const void*)gemm8<0, 12>,
                              hipFuncAttributeMaxDynamicSharedMemorySize, LDSB);
    (void)hipFuncSetAttribute((const void*)gemm8<1, 12>,
                              hipFuncAttributeMaxDynamicSharedMemorySize, LDSB);
    (void)hipFuncSetAttribute((const void*)pv128,
                              hipFuncAttributeMaxDynamicSharedMemorySize, 81920);

    convert_x<<<2048, 256, 0, stream>>>(X, Xb);
    convert_wt<<<dim3(NQKV / 32, DMODEL / 32), 256, 0, stream>>>(W, Wt);
    gemm8<0, 12><<<dim3(64, 8), 512, LDSB, stream>>>(
        Xb, Wt, bias, Qs, Kb, Vt, DMODEL, DMODEL);
    qkv_vtail<<<dim3(128, 2), 256, 0, stream>>>(Xb, Wt, bias, Vt);
    gemm8<1, 12><<<dim3(8, 8, 8), 512, LDSB, stream>>>(
        Qs, Kb, nullptr, S, nullptr, nullptr, DMODEL, DMODEL);
    softmax_rows<<<BATCH * SEQ, 256, 0, stream>>>(S);
    pv128<<<dim3(16, 4, 8), 512, 81920, stream>>>(S, Vt, Out);
}

// Round 14
// 241.347 us; speedup vs baseline: 1.0285x; 1.0285x over previous
//
#include <hip/hip_runtime.h>
#include <hip/hip_bf16.h>

typedef __attribute__((ext_vector_type(8))) short short8;
typedef __attribute__((ext_vector_type(4))) float floatx4;

#define BATCH 8
#define SEQ 2048
#define DMODEL 768
#define NQKV 2304
#define SCALE 0.03608439182435161f

__device__ __forceinline__ ushort f2bf(float f) {
    union { float f; uint u; } in; in.f = f;
    uint u = in.u;
    return (ushort)((u + 0x7FFFu + ((u >> 16) & 1u)) >> 16);
}
__device__ __forceinline__ float bf2f(ushort h) {
    union { uint u; float f; } o; o.u = ((uint)h) << 16;
    return o.f;
}

// async global->LDS, 16B per lane. lds ptr wave-uniform; HW scatters lane*16.
__device__ __forceinline__ void async_copy16(void* lds_uniform, const void* gaddr) {
    __builtin_amdgcn_global_load_lds(
        (const __attribute__((address_space(1))) void*)gaddr,
        (__attribute__((address_space(3))) void*)lds_uniform,
        16, 0, 0);
}

#define BARRIER() asm volatile("s_barrier" ::: "memory")
#define LGKM0()   do { asm volatile("s_waitcnt lgkmcnt(0)" ::: "memory"); \
                       __builtin_amdgcn_sched_barrier(0); } while (0)
#define LGKM_HINT() asm volatile("s_waitcnt lgkmcnt(8)" ::: "memory")
#define VMCNT(n)  asm volatile("s_waitcnt vmcnt(" #n ")" ::: "memory")

// ---------------------------------------------------------------------------
// 256x256 8-phase GEMM template (R6-verified). BK=64, 2 K-tiles/iter, 8 waves
// (2M x 4N), 128KB dynamic LDS, global_load_lds staging with source-side
// chunk-XOR swizzle (slot = c ^ (row&7); ~0 conflicts).
// MODE 0: qkv main, n in [0,2048) only (bias; Q/K row-major; V d<512 -> Vt).
// MODE 1: score (bf16 out). MODE 2: pv (fp32 out).
// Epilogue: row-major per-wave scratch [64][36] fp32 -> dense coalesced stores;
// V-quadrants bypass LDS (fragment-native 8B transposed stores).
// ---------------------------------------------------------------------------
template<int MODE, int KT>
__global__ __launch_bounds__(512, 2) void gemm8(
    const ushort* __restrict__ A, const ushort* __restrict__ B,
    const float* __restrict__ bias,
    void* __restrict__ out0, void* __restrict__ out1, void* __restrict__ out2,
    int lda, int ldb)
{
    extern __shared__ __align__(16) ushort lds[];
    const int tid  = threadIdx.x;
    const int w    = tid >> 6, lane = tid & 63;
    const int wr   = w >> 2,  wc   = w & 3;
    const int lr   = lane & 15, kg = lane >> 4;
    const int srow = lane >> 3;
    const int scc  = (lane & 7) ^ srow;

    const int m0 = blockIdx.x * 256, n0 = blockIdx.y * 256;
    const ushort* Abase;
    const ushort* Bbase;
    if (MODE == 0) {
        Abase = A + (size_t)m0 * lda;
        Bbase = B + (size_t)n0 * ldb;
    } else if (MODE == 1) {
        const int b = blockIdx.z;
        Abase = A + ((size_t)(b * SEQ + m0)) * lda;
        Bbase = B + ((size_t)(b * SEQ + n0)) * ldb;
    } else {
        const int b = blockIdx.z;
        Abase = A + (size_t)b * SEQ * SEQ + (size_t)m0 * lda;
        Bbase = B + (size_t)b * DMODEL * SEQ + (size_t)n0 * ldb;
    }

    const ushort* At[2] = { lds,         lds + 32768 };
    const ushort* Bt[2] = { lds + 16384, lds + 49152 };

    #define STG(tile, mat, half) do { if ((tile) < KT) {                          \
        ushort* sb_ = lds + (((tile) & 1) ? 32768 : 0) + ((mat) ? 16384 : 0);     \
        const ushort* g_ = (mat) ? Bbase : Abase;                                 \
        const size_t ld_ = (mat) ? (size_t)ldb : (size_t)lda;                     \
        const int k0_ = (tile) << 6;                                              \
        _Pragma("unroll")                                                         \
        for (int t_ = 0; t_ < 2; ++t_) {                                          \
            const int c8_ = (mat) ? ((w & 3) + ((w >> 2) << 3) + (t_ << 4) + ((half) << 2)) \
                                  : (w + (t_ << 4) + ((half) << 3));              \
            const int row_ = (c8_ << 3) + srow;                                   \
            async_copy16(sb_ + c8_ * 512, g_ + (size_t)row_ * ld_ + k0_ + scc * 8); \
        } } } while (0)

    short8 af[4][2], bf[4][2];
    floatx4 acc[8][4] = {};

    #define LDFRAG(tp, row, c) \
        (*reinterpret_cast<const short8*>(&(tp)[((row) << 6) + ((((c) ^ ((row) & 7))) << 3)]))

    #define READ_A(bufi, mh) do {                                                 \
        _Pragma("unroll") for (int mf_ = 0; mf_ < 4; ++mf_)                       \
        _Pragma("unroll") for (int kk_ = 0; kk_ < 2; ++kk_)                       \
            af[mf_][kk_] = LDFRAG(At[bufi], wr * 128 + ((mh) * 4 + mf_) * 16 + lr, kk_ * 4 + kg); \
    } while (0)
    #define READ_B(bufi, nh) do {                                                 \
        _Pragma("unroll") for (int nf_ = 0; nf_ < 2; ++nf_)                       \
        _Pragma("unroll") for (int kk_ = 0; kk_ < 2; ++kk_)                       \
            bf[(nh) * 2 + nf_][kk_] = LDFRAG(Bt[bufi], wc * 64 + ((nh) * 2 + nf_) * 16 + lr, kk_ * 4 + kg); \
    } while (0)
    #define MFMA_Q(mh, nh) do {                                                   \
        __builtin_amdgcn_s_setprio(1);                                            \
        _Pragma("unroll") for (int mf_ = 0; mf_ < 4; ++mf_)                       \
        _Pragma("unroll") for (int nf_ = 0; nf_ < 2; ++nf_)                       \
        _Pragma("unroll") for (int kk_ = 0; kk_ < 2; ++kk_)                       \
            acc[(mh) * 4 + mf_][(nh) * 2 + nf_] = __builtin_amdgcn_mfma_f32_16x16x32_bf16( \
                af[mf_][kk_], bf[(nh) * 2 + nf_][kk_], acc[(mh) * 4 + mf_][(nh) * 2 + nf_], 0, 0, 0); \
        __builtin_amdgcn_s_setprio(0);                                            \
    } while (0)

    STG(0, 0, 0); STG(0, 1, 0); STG(0, 1, 1); STG(0, 0, 1);
    STG(1, 0, 0); STG(1, 1, 0); STG(1, 1, 1);
    VMCNT(6);
    BARRIER();

    #pragma unroll 1
    for (int it = 0; it < KT / 2; ++it) {
        const int t = 2 * it;
        const bool lastit = (it == KT / 2 - 1);
        // P1
        READ_A(0, 0); READ_B(0, 0);
        STG(t + 1, 0, 1);
        LGKM_HINT();
        BARRIER(); LGKM0();
        MFMA_Q(0, 0);
        BARRIER();
        // P2
        READ_B(0, 1);
        STG(t + 2, 0, 0);
        BARRIER(); LGKM0();
        MFMA_Q(0, 1);
        BARRIER();
        // P3
        READ_A(0, 1);
        STG(t + 2, 1, 0);
        BARRIER(); LGKM0();
        MFMA_Q(1, 0);
        BARRIER();
        // P4
        STG(t + 2, 1, 1);
        BARRIER();
        MFMA_Q(1, 1);
        if (lastit) { VMCNT(0); } else { VMCNT(6); }
        BARRIER();
        // P5
        READ_A(1, 0); READ_B(1, 0);
        STG(t + 2, 0, 1);
        LGKM_HINT();
        BARRIER(); LGKM0();
        MFMA_Q(0, 0);
        BARRIER();
        // P6
        READ_B(1, 1);
        STG(t + 3, 0, 0);
        BARRIER(); LGKM0();
        MFMA_Q(0, 1);
        BARRIER();
        // P7
        READ_A(1, 1);
        STG(t + 3, 1, 0);
        BARRIER(); LGKM0();
        MFMA_Q(1, 0);
        BARRIER();
        // P8
        STG(t + 3, 1, 1);
        BARRIER();
        MFMA_Q(1, 1);
        VMCNT(6);
        BARRIER();
    }

    // ---- Epilogue ----
    const int mrow = m0 + wr * 128;
    const int ncol = n0 + wc * 64;

    if (MODE == 0 && blockIdx.y >= 6) {
        ushort* Vt = (ushort*)out2;
        const int bIdx = m0 >> 11;
        const int ns0  = m0 & 2047;
        #pragma unroll
        for (int nf = 0; nf < 4; ++nf) {
            const int e = ncol + nf * 16 + lr;        // 1536..2047
            const int d = e - 2 * DMODEL;
            const float bv = bias[e];
            ushort* vrow = Vt + ((size_t)bIdx * DMODEL + d) * SEQ + ns0;
            #pragma unroll
            for (int a = 0; a < 8; ++a) {
                const floatx4 v = acc[a][nf];
                uint2 u;
                u.x = (uint)f2bf(v[0] + bv) | ((uint)f2bf(v[1] + bv) << 16);
                u.y = (uint)f2bf(v[2] + bv) | ((uint)f2bf(v[3] + bv) << 16);
                *reinterpret_cast<uint2*>(vrow + wr * 128 + a * 16 + kg * 4) = u;
            }
        }
    } else {
        float* scr = reinterpret_cast<float*>(reinterpret_cast<char*>(lds) + (size_t)w * 9216);
        #pragma unroll
        for (int mh = 0; mh < 2; ++mh) {
            #pragma unroll
            for (int np = 0; np < 2; ++np) {
                #pragma unroll
                for (int mf = 0; mf < 4; ++mf)
                    #pragma unroll
                    for (int nf2 = 0; nf2 < 2; ++nf2) {
                        const floatx4 v = acc[mh * 4 + mf][np * 2 + nf2];
                        #pragma unroll
                        for (int r = 0; r < 4; ++r)
                            scr[(mf * 16 + kg * 4 + r) * 36 + nf2 * 16 + lr] = v[r];
                    }
                asm volatile("s_waitcnt lgkmcnt(0)" ::: "memory");
                __builtin_amdgcn_sched_barrier(0);

                if (MODE == 2) {
                    float* Ob = (float*)out0 + (size_t)blockIdx.z * SEQ * DMODEL;
                    const int c4 = (lane & 7) * 4;
                    #pragma unroll
                    for (int p = 0; p < 8; ++p) {
                        const int row = p * 8 + (lane >> 3);
                        const float4 v = *reinterpret_cast<const float4*>(&scr[row * 36 + c4]);
                        *reinterpret_cast<float4*>(
                            &Ob[(size_t)(mrow + mh * 64 + row) * DMODEL + ncol + np * 32 + c4]) = v;
                    }
                } else {
                    const int c8 = (lane & 3) * 8;
                    const int e0 = ncol + np * 32 + c8;
                    ushort* dst; int ec; float mul;
                    float bs[8] = {0, 0, 0, 0, 0, 0, 0, 0};
                    if (MODE == 0) {
                        const bool isQ = e0 < DMODEL;
                        dst = isQ ? (ushort*)out0 : (ushort*)out1;
                        ec  = isQ ? e0 : e0 - DMODEL;
                        mul = isQ ? SCALE : 1.0f;
                        const float4 b0 = *reinterpret_cast<const float4*>(&bias[e0]);
                        const float4 b1 = *reinterpret_cast<const float4*>(&bias[e0 + 4]);
                        bs[0] = b0.x * mul; bs[1] = b0.y * mul;
                        bs[2] = b0.z * mul; bs[3] = b0.w * mul;
                        bs[4] = b1.x * mul; bs[5] = b1.y * mul;
                        bs[6] = b1.z * mul; bs[7] = b1.w * mul;
                    } else {
                        dst = (ushort*)out0 + (size_t)blockIdx.z * SEQ * SEQ;
                        ec = e0; mul = 1.0f;
                    }
                    const size_t ostride = (MODE == 0) ? (size_t)DMODEL : (size_t)SEQ;
                    #pragma unroll
                    for (int p = 0; p < 4; ++p) {
                        const int row = p * 16 + (lane >> 2);
                        const float4 lo = *reinterpret_cast<const float4*>(&scr[row * 36 + c8]);
                        const float4 hi = *reinterpret_cast<const float4*>(&scr[row * 36 + c8 + 4]);
                        short8 o;
                        o[0] = (short)f2bf(lo.x * mul + bs[0]);
                        o[1] = (short)f2bf(lo.y * mul + bs[1]);
                        o[2] = (short)f2bf(lo.z * mul + bs[2]);
                        o[3] = (short)f2bf(lo.w * mul + bs[3]);
                        o[4] = (short)f2bf(hi.x * mul + bs[4]);
                        o[5] = (short)f2bf(hi.y * mul + bs[5]);
                        o[6] = (short)f2bf(hi.z * mul + bs[6]);
                        o[7] = (short)f2bf(hi.w * mul + bs[7]);
                        *reinterpret_cast<short8*>(
                            &dst[(size_t)(mrow + mh * 64 + row) * ostride + ec]) = o;
                    }
                }
                asm volatile("s_waitcnt lgkmcnt(0)" ::: "memory");
                __builtin_amdgcn_sched_barrier(0);
            }
        }
    }
    #undef STG
    #undef LDFRAG
    #undef READ_A
    #undef READ_B
    #undef MFMA_Q
}

// ---------------------------------------------------------------------------
// qkv V-tail: cols 2048..2303 (V d in [512,768)). 128x128 tile, BK=32,
// 4 waves, 16KB LDS; V stored transposed to Vt (R8-validated).
// ---------------------------------------------------------------------------
__global__ __launch_bounds__(256) void qkv_vtail(
    const ushort* __restrict__ Xb,
    const ushort* __restrict__ Wt,
    const float* __restrict__ bias,
    ushort* __restrict__ Vt)
{
    __shared__ __align__(16) ushort smem[2 * 128 * 32];
    ushort* As = smem;
    ushort* Bs = smem + 128 * 32;
    const int tid  = threadIdx.x;
    const int m0   = blockIdx.x * 128;
    const int n0   = 2048 + blockIdx.y * 128;
    const int wave = tid >> 6, lane = tid & 63;
    const int wm   = (wave >> 1) * 64, wn = (wave & 1) * 64;
    const int lr   = lane & 15, kg = lane >> 4;
    const ushort* Abase = Xb + (size_t)m0 * DMODEL;
    const ushort* Bbase = Wt + (size_t)n0 * DMODEL;
    floatx4 acc[4][4] = {};

    for (int k0 = 0; k0 < DMODEL; k0 += 32) {
        #pragma unroll
        for (int t = 0; t < 2; ++t) {
            const int chunk = wave * 2 + t;
            const int row = chunk * 16 + (lane >> 2);
            async_copy16(As + chunk * 512,
                         Abase + (size_t)row * DMODEL + k0 + (lane & 3) * 8);
        }
        #pragma unroll
        for (int t = 0; t < 2; ++t) {
            const int chunk = wave * 2 + t;
            const int row = chunk * 16 + (lane >> 2);
            async_copy16(Bs + chunk * 512,
                         Bbase + (size_t)row * DMODEL + k0 + (lane & 3) * 8);
        }
        __syncthreads();
        short8 a[4], b[4];
        #pragma unroll
        for (int i = 0; i < 4; ++i)
            a[i] = *reinterpret_cast<const short8*>(&As[(wm + i * 16 + lr) * 32 + kg * 8]);
        #pragma unroll
        for (int j = 0; j < 4; ++j)
            b[j] = *reinterpret_cast<const short8*>(&Bs[(wn + j * 16 + lr) * 32 + kg * 8]);
        #pragma unroll
        for (int i = 0; i < 4; ++i)
            #pragma unroll
            for (int j = 0; j < 4; ++j)
                acc[i][j] = __builtin_amdgcn_mfma_f32_16x16x32_bf16(a[i], b[j], acc[i][j], 0, 0, 0);
        __syncthreads();
    }

    const int bIdx = m0 >> 11;
    const int ns0  = m0 & 2047;
    #pragma unroll
    for (int j = 0; j < 4; ++j) {
        const int e = n0 + wn + j * 16 + lr;      // 2048..2303
        const int d = e - 2 * DMODEL;             // 512..767
        const float bv = bias[e];
        ushort* vrow = Vt + ((size_t)bIdx * DMODEL + d) * SEQ + ns0;
        #pragma unroll
        for (int i = 0; i < 4; ++i) {
            const floatx4 v = acc[i][j];
            uint2 u;
            u.x = (uint)f2bf(v[0] + bv) | ((uint)f2bf(v[1] + bv) << 16);
            u.y = (uint)f2bf(v[2] + bv) | ((uint)f2bf(v[3] + bv) << 16);
            *reinterpret_cast<uint2*>(vrow + wm + i * 16 + kg * 4) = u;
        }
    }
}

// ---------------------------------------------------------------------------
// Kernel 0a: X fp32 -> bf16
// ---------------------------------------------------------------------------
__global__ __launch_bounds__(256) void convert_x(const float* __restrict__ X,
                                                 ushort* __restrict__ Xb) {
    const int total = (BATCH * SEQ * DMODEL) / 8;
    for (int i = blockIdx.x * 256 + threadIdx.x; i < total; i += gridDim.x * 256) {
        const float4 v0 = reinterpret_cast<const float4*>(X)[(size_t)i * 2];
        const float4 v1 = reinterpret_cast<const float4*>(X)[(size_t)i * 2 + 1];
        uint4 u;
        u.x = (uint)f2bf(v0.x) | ((uint)f2bf(v0.y) << 16);
        u.y = (uint)f2bf(v0.z) | ((uint)f2bf(v0.w) << 16);
        u.z = (uint)f2bf(v1.x) | ((uint)f2bf(v1.y) << 16);
        u.w = (uint)f2bf(v1.z) | ((uint)f2bf(v1.w) << 16);
        reinterpret_cast<uint4*>(Xb)[i] = u;
    }
}

// ---------------------------------------------------------------------------
// Kernel 0b: W [768][2304] fp32 -> Wt [2304][768] bf16 (transpose)
// ---------------------------------------------------------------------------
__global__ __launch_bounds__(256) void convert_wt(const float* __restrict__ W,
                                                  ushort* __restrict__ Wt) {
    __shared__ float tile[32][33];
    const int n0 = blockIdx.x * 32, k0 = blockIdx.y * 32;
    const int tx = threadIdx.x & 31, ty = threadIdx.x >> 5;
    #pragma unroll
    for (int i = 0; i < 32; i += 8)
        tile[ty + i][tx] = W[(size_t)(k0 + ty + i) * NQKV + n0 + tx];
    __syncthreads();
    #pragma unroll
    for (int i = 0; i < 32; i += 8)
        Wt[(size_t)(n0 + ty + i) * DMODEL + k0 + tx] = f2bf(tile[tx][ty + i]);
}

// ---------------------------------------------------------------------------
// Kernel 3: row softmax over 2048, in place, bf16. One block per row.
// ---------------------------------------------------------------------------
__global__ __launch_bounds__(256) void softmax_rows(ushort* __restrict__ S) {
    const int row = blockIdx.x;
    ushort* p = S + (size_t)row * SEQ;
    const int tid = threadIdx.x;
    const int wave = tid >> 6, lane = tid & 63;

    short8 v8 = *reinterpret_cast<const short8*>(p + tid * 8);
    float v[8];
    #pragma unroll
    for (int j = 0; j < 8; ++j) v[j] = bf2f((ushort)v8[j]);
    float mx = v[0];
    #pragma unroll
    for (int j = 1; j < 8; ++j) mx = fmaxf(mx, v[j]);
    #pragma unroll
    for (int off = 32; off >= 1; off >>= 1) mx = fmaxf(mx, __shfl_xor(mx, off));
    __shared__ float redm[4], reds[4];
    if (lane == 0) redm[wave] = mx;
    __syncthreads();
    mx = fmaxf(fmaxf(redm[0], redm[1]), fmaxf(redm[2], redm[3]));

    float e[8], s = 0.f;
    #pragma unroll
    for (int j = 0; j < 8; ++j) { e[j] = __expf(v[j] - mx); s += e[j]; }
    #pragma unroll
    for (int off = 32; off >= 1; off >>= 1) s += __shfl_xor(s, off);
    if (lane == 0) reds[wave] = s;
    __syncthreads();
    s = reds[0] + reds[1] + reds[2] + reds[3];
    float inv = 1.f / s;

    short8 o;
    #pragma unroll
    for (int j = 0; j < 8; ++j) o[j] = (short)f2bf(e[j] * inv);
    *reinterpret_cast<short8*>(p + tid * 8) = o;
}

// ---------------------------------------------------------------------------
extern "C" void kernel_launch(void* const* d_in, const int* in_sizes, int n_in,
                              void* d_out, int out_size, void* d_ws, size_t ws_size,
                              hipStream_t stream) {
    const float* X    = (const float*)d_in[0];
    const float* W    = (const float*)d_in[1];
    const float* bias = (const float*)d_in[2];
    float* Out = (float*)d_out;

    char* ws = (char*)d_ws;
    ushort* S  = (ushort*)ws;
    ushort* Xb = (ushort*)ws;
    ushort* Wt = (ushort*)(ws + (size_t)BATCH * SEQ * DMODEL * 2);
    ushort* Qs = (ushort*)(ws + (size_t)BATCH * SEQ * SEQ * 2);
    ushort* Kb = Qs + (size_t)BATCH * SEQ * DMODEL;
    ushort* Vt = Kb + (size_t)BATCH * SEQ * DMODEL;

    const int LDSB = 131072;
    (void)hipFuncSetAttribute((const void*)gemm8<0, 12>,
                              hipFuncAttributeMaxDynamicSharedMemorySize, LDSB);
    (void)hipFuncSetAttribute((const void*)gemm8<1, 12>,
                              hipFuncAttributeMaxDynamicSharedMemorySize, LDSB);
    (void)hipFuncSetAttribute((const void*)gemm8<2, 32>,
                              hipFuncAttributeMaxDynamicSharedMemorySize, LDSB);

    convert_x<<<2048, 256, 0, stream>>>(X, Xb);
    convert_wt<<<dim3(NQKV / 32, DMODEL / 32), 256, 0, stream>>>(W, Wt);
    gemm8<0, 12><<<dim3(64, 8), 512, LDSB, stream>>>(
        Xb, Wt, bias, Qs, Kb, Vt, DMODEL, DMODEL);
    qkv_vtail<<<dim3(128, 2), 256, 0, stream>>>(Xb, Wt, bias, Vt);
    gemm8<1, 12><<<dim3(8, 8, 8), 512, LDSB, stream>>>(
        Qs, Kb, nullptr, S, nullptr, nullptr, DMODEL, DMODEL);
    softmax_rows<<<BATCH * SEQ, 256, 0, stream>>>(S);
    gemm8<2, 32><<<dim3(8, 3, 8), 512, LDSB, stream>>>(
        S, Vt, nullptr, Out, nullptr, nullptr, SEQ, SEQ);
}